// Round 1
// baseline (69.260 us; speedup 1.0000x reference)
//
#include <hip/hip_runtime.h>

#define KSZ 5
#define PAD 2
#define TILE 16
#define LTS (TILE + 2 * PAD)   // 20

__global__ __launch_bounds__(256) void denoise_median5_kernel(
    const float* __restrict__ x,
    const float* __restrict__ noise_var_p,
    const float* __restrict__ noise_bias_p,
    float* __restrict__ out,
    int H, int W)
{
    __shared__ float tile[LTS][LTS];

    const float noise_var  = noise_var_p[0];
    const float noise_bias = noise_bias_p[0];

    const int b      = blockIdx.z;
    const int tile_y = blockIdx.y * TILE;
    const int tile_x = blockIdx.x * TILE;
    const int tx = threadIdx.x;
    const int ty = threadIdx.y;

    const float* __restrict__ img = x + (size_t)b * H * W;

    // Stage LTS x LTS zero-padded tile into LDS.
    for (int idx = ty * TILE + tx; idx < LTS * LTS; idx += TILE * TILE) {
        const int ly = idx / LTS;
        const int lx = idx - ly * LTS;
        const int gy = tile_y + ly - PAD;
        const int gx = tile_x + lx - PAD;
        float v = 0.0f;
        if (gy >= 0 && gy < H && gx >= 0 && gx < W)
            v = img[gy * W + gx];
        tile[ly][lx] = v;
    }
    __syncthreads();

    // Gather the 25 window values into registers (fully unrolled, static idx).
    float v[KSZ * KSZ];
    #pragma unroll
    for (int i = 0; i < KSZ; ++i) {
        #pragma unroll
        for (int j = 0; j < KSZ; ++j) {
            v[i * KSZ + j] = tile[ty + i][tx + j];
        }
    }

    const float xc = v[12];   // center pixel (i=2, j=2)

    // Unbiased variance over the 25 window values (ddof=1).
    float sum = 0.0f, sumsq = 0.0f;
    #pragma unroll
    for (int i = 0; i < KSZ * KSZ; ++i) {
        sum   += v[i];
        sumsq += v[i] * v[i];
    }
    const float mean = sum * (1.0f / 25.0f);
    float var = (sumsq - sum * mean) * (1.0f / 24.0f);
    var = fmaxf(var, 0.0f);

    // Median = 13th smallest of 25 via partial selection (compare-exchange).
    #pragma unroll
    for (int i = 0; i < 13; ++i) {
        #pragma unroll
        for (int j = i + 1; j < KSZ * KSZ; ++j) {
            const float lo = fminf(v[i], v[j]);
            const float hi = fmaxf(v[i], v[j]);
            v[i] = lo;
            v[j] = hi;
        }
    }
    const float mid = v[12];

    float y = xc - noise_var / (var + 1e-10f) * (xc - mid + noise_bias);
    y = fmaxf(y, 0.0f);

    const int gy = tile_y + ty;
    const int gx = tile_x + tx;
    out[(size_t)b * H * W + gy * W + gx] = y;
}

extern "C" void kernel_launch(void* const* d_in, const int* in_sizes, int n_in,
                              void* d_out, int out_size, void* d_ws, size_t ws_size,
                              hipStream_t stream)
{
    const float* x  = (const float*)d_in[0];
    const float* nv = (const float*)d_in[1];
    const float* nb = (const float*)d_in[2];
    float* out = (float*)d_out;

    const int H = 512, W = 512;
    const int B = in_sizes[0] / (H * W);   // 16 (C==1)

    dim3 block(TILE, TILE, 1);
    dim3 grid(W / TILE, H / TILE, B);
    denoise_median5_kernel<<<grid, block, 0, stream>>>(x, nv, nb, out, H, W);
}

// Round 2
// 43.329 us; speedup vs baseline: 1.5985x; 1.5985x over previous
//
#include <hip/hip_runtime.h>

#define PAD 2
#define PX 4                 // pixels per thread along x
#define BDX 16
#define BDY 16
#define TSX (BDX * PX)       // 64 outputs wide per block
#define TSY BDY              // 16 outputs high per block
#define LTW (TSX + 2 * PAD)  // 68
#define LTH (TSY + 2 * PAD)  // 20

// compare-exchange: a <- min, b <- max
#define CE(a, b) { float _lo = fminf(a, b), _hi = fmaxf(a, b); (a) = _lo; (b) = _hi; }

// full sort of 5 (Knuth optimal 9-CE network, verified)
#define SORT5(t0, t1, t2, t3, t4) \
    CE(t0, t1) CE(t3, t4) CE(t2, t4) CE(t2, t3) CE(t0, t3) \
    CE(t0, t2) CE(t1, t4) CE(t1, t3) CE(t1, t2)

// place max at t4, 2nd-largest at t3 (two independent max reductions; correct by construction)
#define TOP2(t0, t1, t2, t3, t4) \
    CE(t0, t1) CE(t2, t3) CE(t1, t3) CE(t3, t4) \
    CE(t0, t1) CE(t2, t3) CE(t1, t3)

// place min at t0, 2nd-smallest at t1
#define BOT2(t0, t1, t2, t3, t4) \
    CE(t0, t1) CE(t2, t3) CE(t0, t2) CE(t0, t4) \
    CE(t1, t2) CE(t3, t4) CE(t1, t3)

__global__ __launch_bounds__(256) void denoise_median5_kernel(
    const float* __restrict__ x,
    const float* __restrict__ noise_var_p,
    const float* __restrict__ noise_bias_p,
    float* __restrict__ out,
    int H, int W)
{
    __shared__ float tile[LTH][LTW];

    const float noise_var  = noise_var_p[0];
    const float noise_bias = noise_bias_p[0];

    const int b      = blockIdx.z;
    const int tile_y = blockIdx.y * TSY;
    const int tile_x = blockIdx.x * TSX;
    const int tx = threadIdx.x;
    const int ty = threadIdx.y;
    const int tid = ty * BDX + tx;

    const float* __restrict__ img = x + (size_t)b * H * W;

    // Stage LTH x LTW zero-padded tile into LDS.
    for (int i = tid; i < LTH * LTW; i += BDX * BDY) {
        const int ly = i / LTW;
        const int lx = i - ly * LTW;
        const int gy = tile_y + ly - PAD;
        const int gx = tile_x + lx - PAD;
        float v = 0.0f;
        if (gy >= 0 && gy < H && gx >= 0 && gx < W)
            v = img[gy * W + gx];
        tile[ly][lx] = v;
    }
    __syncthreads();

    // Each thread: 8 columns x 5 rows covering its PX=4 output pixels.
    // LDS col base = tx*PX (aligned 16B since LTW%4==0 and base%4==0).
    float c[PX + 4][5];
    #pragma unroll
    for (int r = 0; r < 5; ++r) {
        const float* rowp = &tile[ty + r][tx * PX];
        const float4 a = *(const float4*)(rowp);
        const float4 d = *(const float4*)(rowp + 4);
        c[0][r] = a.x; c[1][r] = a.y; c[2][r] = a.z; c[3][r] = a.w;
        c[4][r] = d.x; c[5][r] = d.y; c[6][r] = d.z; c[7][r] = d.w;
    }

    // Center pixel values (before the in-place column sorts destroy positions).
    float center[PX];
    #pragma unroll
    for (int p = 0; p < PX; ++p) center[p] = c[p + 2][2];

    // Sort all 8 columns (shared across the 4 windows).
    #pragma unroll
    for (int k = 0; k < PX + 4; ++k) {
        SORT5(c[k][0], c[k][1], c[k][2], c[k][3], c[k][4]);
    }

    // Per-column sum and sum-of-squares (sum is sort-invariant) for variance.
    float s[PX + 4], q[PX + 4];
    #pragma unroll
    for (int k = 0; k < PX + 4; ++k) {
        s[k] = ((c[k][0] + c[k][1]) + (c[k][2] + c[k][3])) + c[k][4];
        float qq = c[k][0] * c[k][0];
        qq = fmaf(c[k][1], c[k][1], qq);
        qq = fmaf(c[k][2], c[k][2], qq);
        qq = fmaf(c[k][3], c[k][3], qq);
        qq = fmaf(c[k][4], c[k][4], qq);
        q[k] = qq;
    }

    float4 res;
    float* resp = (float*)&res;

    #pragma unroll
    for (int p = 0; p < PX; ++p) {
        // ---- median of the 5x5 window = rank-7 of the 13 candidates of the
        //      doubly-sorted matrix (columns sorted above, rows sorted here) ----
        float w0, w1, w2, w3, w4, w5, w6, w7, w8, w9, w10, w11, w12;
        {
            // row 0: need sorted positions 3,4 (2nd-largest, largest)
            float t0 = c[p][0], t1 = c[p+1][0], t2 = c[p+2][0], t3 = c[p+3][0], t4 = c[p+4][0];
            TOP2(t0, t1, t2, t3, t4);
            w0 = t3; w1 = t4;
        }
        {
            // row 1: need sorted positions 2,3,4
            float t0 = c[p][1], t1 = c[p+1][1], t2 = c[p+2][1], t3 = c[p+3][1], t4 = c[p+4][1];
            SORT5(t0, t1, t2, t3, t4);
            w2 = t2; w3 = t3; w4 = t4;
        }
        {
            // row 2: need sorted positions 1,2,3
            float t0 = c[p][2], t1 = c[p+1][2], t2 = c[p+2][2], t3 = c[p+3][2], t4 = c[p+4][2];
            SORT5(t0, t1, t2, t3, t4);
            w5 = t1; w6 = t2; w7 = t3;
        }
        {
            // row 3: need sorted positions 0,1,2
            float t0 = c[p][3], t1 = c[p+1][3], t2 = c[p+2][3], t3 = c[p+3][3], t4 = c[p+4][3];
            SORT5(t0, t1, t2, t3, t4);
            w8 = t0; w9 = t1; w10 = t2;
        }
        {
            // row 4: need sorted positions 0,1 (min, 2nd-smallest)
            float t0 = c[p][4], t1 = c[p+1][4], t2 = c[p+2][4], t3 = c[p+3][4], t4 = c[p+4][4];
            BOT2(t0, t1, t2, t3, t4);
            w11 = t0; w12 = t1;
        }

        // rank-7 (median) of the 13 candidates: selection-sort prefix, w6' ends
        // as the 7th smallest. Naive 63-CE partial selection (provably correct).
        float w[13] = {w0, w1, w2, w3, w4, w5, w6, w7, w8, w9, w10, w11, w12};
        #pragma unroll
        for (int i = 0; i < 7; ++i) {
            #pragma unroll
            for (int j = i + 1; j < 13; ++j) {
                CE(w[i], w[j]);
            }
        }
        const float mid = w[6];

        // ---- unbiased variance from shared column sums ----
        const float sum = ((s[p] + s[p+1]) + (s[p+2] + s[p+3])) + s[p+4];
        const float sq  = ((q[p] + q[p+1]) + (q[p+2] + q[p+3])) + q[p+4];
        const float mean = sum * (1.0f / 25.0f);
        float var = (sq - sum * mean) * (1.0f / 24.0f);
        var = fmaxf(var, 0.0f);

        const float xc = center[p];
        float y = xc - noise_var / (var + 1e-10f) * (xc - mid + noise_bias);
        resp[p] = fmaxf(y, 0.0f);
    }

    const int gy = tile_y + ty;
    const int gx = tile_x + tx * PX;
    *(float4*)&out[((size_t)b * H + gy) * W + gx] = res;
}

extern "C" void kernel_launch(void* const* d_in, const int* in_sizes, int n_in,
                              void* d_out, int out_size, void* d_ws, size_t ws_size,
                              hipStream_t stream)
{
    const float* x  = (const float*)d_in[0];
    const float* nv = (const float*)d_in[1];
    const float* nb = (const float*)d_in[2];
    float* out = (float*)d_out;

    const int H = 512, W = 512;
    const int B = in_sizes[0] / (H * W);   // 16 (C==1)

    dim3 block(BDX, BDY, 1);
    dim3 grid(W / TSX, H / TSY, B);
    denoise_median5_kernel<<<grid, block, 0, stream>>>(x, nv, nb, out, H, W);
}

// Round 3
// 32.800 us; speedup vs baseline: 2.1116x; 1.3210x over previous
//
#include <hip/hip_runtime.h>

#define PAD 2
#define PX 4                 // pixels per thread along x
#define BDX 16
#define BDY 16
#define TSX (BDX * PX)       // 64 outputs wide per block
#define TSY BDY              // 16 outputs high per block
#define LTW (TSX + 2 * PAD)  // 68
#define LTH (TSY + 2 * PAD)  // 20

// compare-exchange: a <- min, b <- max  (dead outputs are DCE'd by the compiler)
#define CE(a, b) { float _lo = fminf(a, b), _hi = fmaxf(a, b); (a) = _lo; (b) = _hi; }

// full sort of 5 (Knuth optimal 9-CE network)
#define SORT5(t0, t1, t2, t3, t4) \
    CE(t0, t1) CE(t3, t4) CE(t2, t4) CE(t2, t3) CE(t0, t3) \
    CE(t0, t2) CE(t1, t4) CE(t1, t3) CE(t1, t2)

// place max at t4, 2nd-largest at t3 (exact order statistics)
#define TOP2(t0, t1, t2, t3, t4) \
    CE(t0, t1) CE(t2, t3) CE(t1, t3) CE(t3, t4) \
    CE(t0, t1) CE(t2, t3) CE(t1, t3)

// place min at t0, 2nd-smallest at t1 (exact order statistics)
#define BOT2(t0, t1, t2, t3, t4) \
    CE(t0, t1) CE(t2, t3) CE(t0, t2) CE(t0, t4) \
    CE(t1, t2) CE(t3, t4) CE(t1, t3)

// median of 9 in q4 (Devillard 19-CE network)
#define MED9(q0, q1, q2, q3, q4, q5, q6, q7, q8) \
    CE(q1, q2) CE(q4, q5) CE(q7, q8) \
    CE(q0, q1) CE(q3, q4) CE(q6, q7) \
    CE(q1, q2) CE(q4, q5) CE(q7, q8) \
    CE(q0, q3) CE(q5, q8) CE(q4, q7) \
    CE(q3, q6) CE(q1, q4) CE(q2, q5) \
    CE(q4, q7) CE(q4, q2) CE(q6, q4) \
    CE(q4, q2)

__global__ __launch_bounds__(256) void denoise_median5_kernel(
    const float* __restrict__ x,
    const float* __restrict__ noise_var_p,
    const float* __restrict__ noise_bias_p,
    float* __restrict__ out,
    int H, int W)
{
    __shared__ float tile[LTH][LTW];

    const float noise_var  = noise_var_p[0];
    const float noise_bias = noise_bias_p[0];

    const int b      = blockIdx.z;
    const int tile_y = blockIdx.y * TSY;
    const int tile_x = blockIdx.x * TSX;
    const int tx = threadIdx.x;
    const int ty = threadIdx.y;
    const int tid = ty * BDX + tx;

    const float* __restrict__ img = x + (size_t)b * H * W;

    // Stage LTH x LTW zero-padded tile into LDS.
    for (int i = tid; i < LTH * LTW; i += BDX * BDY) {
        const int ly = i / LTW;
        const int lx = i - ly * LTW;
        const int gy = tile_y + ly - PAD;
        const int gx = tile_x + lx - PAD;
        float v = 0.0f;
        if (gy >= 0 && gy < H && gx >= 0 && gx < W)
            v = img[gy * W + gx];
        tile[ly][lx] = v;
    }
    __syncthreads();

    // Each thread: 8 columns x 5 rows covering its PX=4 output pixels.
    float c[PX + 4][5];
    #pragma unroll
    for (int r = 0; r < 5; ++r) {
        const float* rowp = &tile[ty + r][tx * PX];
        const float4 a = *(const float4*)(rowp);
        const float4 d = *(const float4*)(rowp + 4);
        c[0][r] = a.x; c[1][r] = a.y; c[2][r] = a.z; c[3][r] = a.w;
        c[4][r] = d.x; c[5][r] = d.y; c[6][r] = d.z; c[7][r] = d.w;
    }

    // Center pixel values (before the in-place column sorts destroy positions).
    float center[PX];
    #pragma unroll
    for (int p = 0; p < PX; ++p) center[p] = c[p + 2][2];

    // Sort all 8 columns (shared across the 4 windows).
    #pragma unroll
    for (int k = 0; k < PX + 4; ++k) {
        SORT5(c[k][0], c[k][1], c[k][2], c[k][3], c[k][4]);
    }

    // Per-column sum and sum-of-squares (sort-invariant) for variance.
    float s[PX + 4], q[PX + 4];
    #pragma unroll
    for (int k = 0; k < PX + 4; ++k) {
        s[k] = ((c[k][0] + c[k][1]) + (c[k][2] + c[k][3])) + c[k][4];
        float qq = c[k][0] * c[k][0];
        qq = fmaf(c[k][1], c[k][1], qq);
        qq = fmaf(c[k][2], c[k][2], qq);
        qq = fmaf(c[k][3], c[k][3], qq);
        qq = fmaf(c[k][4], c[k][4], qq);
        q[k] = qq;
    }

    // Sliding 5-wide sums across the 4 pixels.
    float sum5[PX], sq5[PX];
    sum5[0] = ((s[0] + s[1]) + (s[2] + s[3])) + s[4];
    sq5[0]  = ((q[0] + q[1]) + (q[2] + q[3])) + q[4];
    #pragma unroll
    for (int p = 1; p < PX; ++p) {
        sum5[p] = sum5[p - 1] - s[p - 1] + s[p + 4];
        sq5[p]  = sq5[p - 1]  - q[p - 1] + q[p + 4];
    }

    float4 res;
    float* resp = (float*)&res;

    #pragma unroll
    for (int p = 0; p < PX; ++p) {
        // ---- rows of the doubly-sorted 5x5: extract needed order statistics ----
        float A1, A2;            // row0 sorted pos 3,4
        {
            float t0 = c[p][0], t1 = c[p+1][0], t2 = c[p+2][0], t3 = c[p+3][0], t4 = c[p+4][0];
            TOP2(t0, t1, t2, t3, t4);
            A1 = t3; A2 = t4;
        }
        float B1, B2, B3;        // row1 sorted pos 2,3,4
        {
            float t0 = c[p][1], t1 = c[p+1][1], t2 = c[p+2][1], t3 = c[p+3][1], t4 = c[p+4][1];
            SORT5(t0, t1, t2, t3, t4);
            B1 = t2; B2 = t3; B3 = t4;
        }
        float C1, C2, C3;        // row2 sorted pos 1,2,3
        {
            float t0 = c[p][2], t1 = c[p+1][2], t2 = c[p+2][2], t3 = c[p+3][2], t4 = c[p+4][2];
            SORT5(t0, t1, t2, t3, t4);
            C1 = t1; C2 = t2; C3 = t3;
        }
        float D1, D2, D3;        // row3 sorted pos 0,1,2
        {
            float t0 = c[p][3], t1 = c[p+1][3], t2 = c[p+2][3], t3 = c[p+3][3], t4 = c[p+4][3];
            SORT5(t0, t1, t2, t3, t4);
            D1 = t0; D2 = t1; D3 = t2;
        }
        float E1, E2;            // row4 sorted pos 0,1
        {
            float t0 = c[p][4], t1 = c[p+1][4], t2 = c[p+2][4], t3 = c[p+3][4], t4 = c[p+4][4];
            BOT2(t0, t1, t2, t3, t4);
            E1 = t0; E2 = t1;
        }

        // ---- poset elimination (rank-counted, provably not-median elements dropped):
        // max(B3,D3) and max(C3,E2) have >=9 elements below -> rank>=10;
        // min(B1,D1) and min(A1,C1) have >=9 elements above -> rank<=4.
        // Median of 13 = median (rank 5) of the 9 survivors.
        const float mn1 = fminf(B3, D3);
        const float mn2 = fminf(C3, E2);
        const float mx1 = fmaxf(B1, D1);
        const float mx2 = fmaxf(A1, C1);

        float q0 = mx2, q1 = A2, q2 = B2, q3 = C2, q4 = D2,
              q5 = E1, q6 = mx1, q7 = mn1, q8 = mn2;
        MED9(q0, q1, q2, q3, q4, q5, q6, q7, q8);
        const float mid = q4;

        // ---- unbiased variance from shared column sums ----
        const float sum = sum5[p];
        const float sq  = sq5[p];
        const float mean = sum * (1.0f / 25.0f);
        float var = (sq - sum * mean) * (1.0f / 24.0f);
        var = fmaxf(var, 0.0f);

        const float xc = center[p];
        const float r = __builtin_amdgcn_rcpf(var + 1e-10f);
        float y = xc - noise_var * r * (xc - mid + noise_bias);
        resp[p] = fmaxf(y, 0.0f);
    }

    const int gy = tile_y + ty;
    const int gx = tile_x + tx * PX;
    *(float4*)&out[((size_t)b * H + gy) * W + gx] = res;
}

extern "C" void kernel_launch(void* const* d_in, const int* in_sizes, int n_in,
                              void* d_out, int out_size, void* d_ws, size_t ws_size,
                              hipStream_t stream)
{
    const float* x  = (const float*)d_in[0];
    const float* nv = (const float*)d_in[1];
    const float* nb = (const float*)d_in[2];
    float* out = (float*)d_out;

    const int H = 512, W = 512;
    const int B = in_sizes[0] / (H * W);   // 16 (C==1)

    dim3 block(BDX, BDY, 1);
    dim3 grid(W / TSX, H / TSY, B);
    denoise_median5_kernel<<<grid, block, 0, stream>>>(x, nv, nb, out, H, W);
}